// Round 5
// baseline (79.922 us; speedup 1.0000x reference)
//
#include <hip/hip_runtime.h>
#include <hip/hip_bf16.h>

#define VOCAB 100000
#define HALF  256      // HIDDEN/2
#define NC    256      // NUM_CLUSTERS
#define NTOK  16384    // B*S
#define TPB   16       // tokens per block
#define CK    16       // cluster rows staged per chunk
#define NBUCK 2048     // id>>6 -> 0..1562, padded to 2048

// ---------------- sort prework ----------------
__global__ __launch_bounds__(1024)
void hist_kernel(const int* __restrict__ ids, int* __restrict__ hist) {
    const int t = blockIdx.x * 1024 + threadIdx.x;
    atomicAdd(&hist[ids[t] >> 6], 1);
}

__global__ __launch_bounds__(1024)
void scan_kernel(const int* __restrict__ hist, int* __restrict__ offs) {
    __shared__ int part[1024];
    const int tid = threadIdx.x;
    const int h0 = hist[2 * tid], h1 = hist[2 * tid + 1];
    part[tid] = h0 + h1;
    __syncthreads();
    for (int off = 1; off < 1024; off <<= 1) {
        const int v   = part[tid];
        const int add = (tid >= off) ? part[tid - off] : 0;
        __syncthreads();
        part[tid] = v + add;
        __syncthreads();
    }
    const int excl = (tid == 0) ? 0 : part[tid - 1];
    offs[2 * tid]     = excl;
    offs[2 * tid + 1] = excl + h0;
}

__global__ __launch_bounds__(1024)
void scatter_kernel(const int* __restrict__ ids, int* __restrict__ offs,
                    int* __restrict__ sorted) {
    const int t = blockIdx.x * 1024 + threadIdx.x;
    const int pos = atomicAdd(&offs[ids[t] >> 6], 1);
    sorted[pos] = t;
}

// ---------------- main fused kernel ----------------
// LDS = 8 KB distT(bf16) + 16 KB cw_tile + 128 B ids = 24.7 KB -> 4 blocks/CU (32 waves)
__global__ __launch_bounds__(512, 8)
void hle_fused(const int*   __restrict__ ids,
               const float* __restrict__ fine_w,     // [VOCAB, HALF]
               const float* __restrict__ coarse_w,   // [NC, HALF]
               const float* __restrict__ cluster_w,  // [NC, VOCAB]
               const float* __restrict__ cluster_b,  // [NC]
               const int*   __restrict__ sorted,     // [NTOK] token order by id
               float*       __restrict__ out)        // [NTOK, 512]
{
    __shared__ __hip_bfloat16 distT[NC][TPB];   // slot t stored at distT[c][t ^ (c&14)]
    __shared__ float cw_tile[CK][HALF];
    __shared__ int   sid_tok[TPB];
    __shared__ int   sid_id[TPB];

    const int tid  = threadIdx.x;
    const int wave = tid >> 6;   // 0..7
    const int lane = tid & 63;
    const int base = blockIdx.x * TPB;

    if (tid < TPB) {
        const int tok = sorted[base + tid];
        sid_tok[tid] = tok;
        sid_id[tid]  = ids[tok];
    }
    __syncthreads();

    // ---------------- Phase 1a: row-sliced logit gather ----------------
    // lane = (rp, token): 16 SORTED ids x 4 rows per instruction; 8 loads in flight.
    {
        const int tl = lane & 15;       // local token slot
        const int rp = lane >> 4;       // 0..3 row offset
        const int id = sid_id[tl];
        const int c0 = rp + 4 * wave;   // rows c0 + 32k cover 0..255

        float lg[8];
#pragma unroll
        for (int k = 0; k < 8; ++k)
            lg[k] = cluster_w[(size_t)(c0 + 32 * k) * VOCAB + id];

#pragma unroll
        for (int k = 0; k < 8; ++k) {
            const int c = c0 + 32 * k;
            distT[c][tl ^ (c & 14)] = __float2bfloat16(lg[k] + cluster_b[c]);
        }
    }
    __syncthreads();

    // ---------------- Phase 1b: softmax (wave -> 2 tokens) + fine gather ----------------
    {
#pragma unroll
        for (int i = 0; i < 2; ++i) {
            const int t = 2 * wave + i;
            float v[4];
#pragma unroll
            for (int k = 0; k < 4; ++k) {
                const int c = lane + 64 * k;
                v[k] = __bfloat162float(distT[c][t ^ (c & 14)]);   // 2-way: free
            }
            float m = fmaxf(fmaxf(v[0], v[1]), fmaxf(v[2], v[3]));
#pragma unroll
            for (int off = 32; off >= 1; off >>= 1) m = fmaxf(m, __shfl_xor(m, off));
            float e[4], s = 0.f;
#pragma unroll
            for (int k = 0; k < 4; ++k) { e[k] = __expf(v[k] - m); s += e[k]; }
#pragma unroll
            for (int off = 32; off >= 1; off >>= 1) s += __shfl_xor(s, off);
            const float inv = 1.f / s;
#pragma unroll
            for (int k = 0; k < 4; ++k) {
                const int c = lane + 64 * k;
                distT[c][t ^ (c & 14)] = __float2bfloat16(e[k] * inv);
            }
            // fine half of output (coalesced 1KB row per token)
            const float4 f = *reinterpret_cast<const float4*>(
                fine_w + (size_t)sid_id[t] * HALF + lane * 4);
            *reinterpret_cast<float4*>(out + (size_t)sid_tok[t] * 512 + lane * 4) = f;
        }
    }

    // ---------------- Phase 2: coarse mixture, LDS-staged coarse_w ----------------
    float acc[2][4] = {{0.f, 0.f, 0.f, 0.f}, {0.f, 0.f, 0.f, 0.f}};
    const int t0 = 2 * wave;
    const int colbase = lane * 4;

    for (int ch = 0; ch < NC / CK; ++ch) {
        __syncthreads();   // prev chunk consumed (and, at ch=0, distT normalized)
        {
            // stage CK x 256 f32 = 1024 float4; 512 threads -> 2 each
            const float4* src = reinterpret_cast<const float4*>(coarse_w + (size_t)ch * CK * HALF);
            float4* dst = reinterpret_cast<float4*>(&cw_tile[0][0]);
            dst[tid]       = src[tid];
            dst[tid + 512] = src[tid + 512];
        }
        __syncthreads();

#pragma unroll
        for (int j = 0; j < CK; ++j) {
            const int cc = ch * CK + j;
            // 2 dist values (tokens t0, t0+1), pair-aligned under swizzle
            const __hip_bfloat162 dpk =
                *reinterpret_cast<const __hip_bfloat162*>(&distT[cc][t0 ^ (cc & 14)]);
            const float2 d = __bfloat1622float2(dpk);
            const float4 v = *reinterpret_cast<const float4*>(&cw_tile[j][colbase]);
            acc[0][0] = fmaf(d.x, v.x, acc[0][0]);
            acc[0][1] = fmaf(d.x, v.y, acc[0][1]);
            acc[0][2] = fmaf(d.x, v.z, acc[0][2]);
            acc[0][3] = fmaf(d.x, v.w, acc[0][3]);
            acc[1][0] = fmaf(d.y, v.x, acc[1][0]);
            acc[1][1] = fmaf(d.y, v.y, acc[1][1]);
            acc[1][2] = fmaf(d.y, v.z, acc[1][2]);
            acc[1][3] = fmaf(d.y, v.w, acc[1][3]);
        }
    }

    // epilogue: coarse half of output at original token rows
#pragma unroll
    for (int i = 0; i < 2; ++i) {
        float* o = out + (size_t)sid_tok[t0 + i] * 512 + 256 + colbase;
        *reinterpret_cast<float4*>(o) = make_float4(acc[i][0], acc[i][1], acc[i][2], acc[i][3]);
    }
}

extern "C" void kernel_launch(void* const* d_in, const int* in_sizes, int n_in,
                              void* d_out, int out_size, void* d_ws, size_t ws_size,
                              hipStream_t stream) {
    const int*   ids       = (const int*)  d_in[0];
    const float* fine_w    = (const float*)d_in[1];
    const float* coarse_w  = (const float*)d_in[2];
    const float* cluster_w = (const float*)d_in[3];
    const float* cluster_b = (const float*)d_in[4];
    float*       out       = (float*)d_out;

    int* offs   = (int*)d_ws;                 // [NBUCK]
    int* hist   = offs + NBUCK;               // [NBUCK]
    int* sorted = hist + NBUCK;               // [NTOK]

    hipMemsetAsync(hist, 0, NBUCK * sizeof(int), stream);
    hipLaunchKernelGGL(hist_kernel,    dim3(NTOK / 1024), dim3(1024), 0, stream, ids, hist);
    hipLaunchKernelGGL(scan_kernel,    dim3(1),           dim3(1024), 0, stream, hist, offs);
    hipLaunchKernelGGL(scatter_kernel, dim3(NTOK / 1024), dim3(1024), 0, stream, ids, offs, sorted);
    hipLaunchKernelGGL(hle_fused,      dim3(NTOK / TPB),  dim3(512),  0, stream,
                       ids, fine_w, coarse_w, cluster_w, cluster_b, sorted, out);
}

// Round 6
// 77.771 us; speedup vs baseline: 1.0277x; 1.0277x over previous
//
#include <hip/hip_runtime.h>
#include <hip/hip_bf16.h>

#define VOCAB 100000
#define HALF  256      // HIDDEN/2
#define NC    256      // NUM_CLUSTERS
#define NTOK  16384    // B*S
#define NBUCK 2048     // id>>6 -> 0..1562, padded
#define SEGSZ 3200     // ids per segment (= 50 buckets of 64)
#define NSEG  32       // ceil(100000/3200)
#define BPS   50       // buckets per segment

// ---------------- sort prework ----------------
__global__ __launch_bounds__(1024)
void hist_kernel(const int* __restrict__ ids, int* __restrict__ hist) {
    const int t = blockIdx.x * 1024 + threadIdx.x;
    atomicAdd(&hist[ids[t] >> 6], 1);
}

__global__ __launch_bounds__(1024)
void scan_kernel(const int* __restrict__ hist, int* __restrict__ offs,
                 int* __restrict__ bexcl) {
    __shared__ int part[1024];
    const int tid = threadIdx.x;
    const int h0 = hist[2 * tid], h1 = hist[2 * tid + 1];
    part[tid] = h0 + h1;
    __syncthreads();
    for (int off = 1; off < 1024; off <<= 1) {
        const int v   = part[tid];
        const int add = (tid >= off) ? part[tid - off] : 0;
        __syncthreads();
        part[tid] = v + add;
        __syncthreads();
    }
    const int excl = (tid == 0) ? 0 : part[tid - 1];
    offs[2 * tid]      = excl;
    offs[2 * tid + 1]  = excl + h0;
    bexcl[2 * tid]     = excl;          // immutable copy for segment ranges
    bexcl[2 * tid + 1] = excl + h0;
}

__global__ __launch_bounds__(1024)
void scatter_kernel(const int* __restrict__ ids, int* __restrict__ offs,
                    int* __restrict__ stok, int* __restrict__ sidv) {
    const int t = blockIdx.x * 1024 + threadIdx.x;
    const int id = ids[t];
    const int pos = atomicAdd(&offs[id >> 6], 1);
    stok[pos] = t;
    sidv[pos] = id;
}

// ---------------- Kernel A: streaming logit gather ----------------
// block = (row r, segment s): stage cluster_w[r][seg] coalesced into LDS,
// then for sorted slots whose id falls in the segment, lookup + write
// logitsT[r][slot] (bf16, coalesced). All global traffic is streaming.
__global__ __launch_bounds__(256)
void gather_rows(const float* __restrict__ cluster_w,
                 const float* __restrict__ cluster_b,
                 const int*   __restrict__ sidv,
                 const int*   __restrict__ bexcl,
                 __hip_bfloat16* __restrict__ logT)      // [NC][NTOK]
{
    __shared__ float seg[SEGSZ];
    const int bid = blockIdx.x;
    const int r   = bid >> 5;          // 0..255
    const int s   = bid & 31;          // 0..31
    const int tid = threadIdx.x;
    const int sbase = s * SEGSZ;
    const int slen  = min(SEGSZ, VOCAB - sbase);   // 3200 or 800 (last)

    const float4* src = reinterpret_cast<const float4*>(cluster_w + (size_t)r * VOCAB + sbase);
    float4* dst = reinterpret_cast<float4*>(seg);
    const int nf4 = slen >> 2;
    for (int i = tid; i < nf4; i += 256) dst[i] = src[i];

    const float bias = cluster_b[r];
    const int lo = bexcl[s * BPS];
    const int hi = bexcl[(s + 1) * BPS];
    __syncthreads();

    for (int i = lo + tid; i < hi; i += 256) {
        const int id = sidv[i];
        logT[(size_t)r * NTOK + i] = __float2bfloat16(seg[id - sbase] + bias);
    }
}

// ---------------- Kernel B: softmax + fine + mixture ----------------
// 512 threads, 64 slots/block, grid 256. LDS ~51 KB.
__global__ __launch_bounds__(512)
void mix_fine(const __hip_bfloat16* __restrict__ logT,
              const float* __restrict__ fine_w,
              const float* __restrict__ coarse_w,
              const int*   __restrict__ stok,
              const int*   __restrict__ sidv,
              float*       __restrict__ out)
{
    __shared__ __hip_bfloat16 ldsDist[NC][64];   // 32 KB, [cluster][slot]
    __shared__ float cw[16][HALF];               // 16 KB chunk of coarse_w
    __shared__ float part[64][9];                // padded partials
    __shared__ int stok_l[64], sid_l[64];

    const int tid  = threadIdx.x;
    const int g    = tid >> 6;    // wave 0..7 (c-group in B1, slot-group in B2)
    const int s    = tid & 63;    // lane = slot in B1, col-group in B2
    const int base = blockIdx.x * 64;

    if (tid < 64) { stok_l[tid] = stok[base + tid]; sid_l[tid] = sidv[base + tid]; }

    // prefetch coarse chunk 0 into regs (double-buffer via registers)
    float4 pre0 = reinterpret_cast<const float4*>(coarse_w)[tid];
    float4 pre1 = reinterpret_cast<const float4*>(coarse_w)[tid + 512];

    // ---- B1: softmax over c for slot base+s; thread owns c = g*32..g*32+31 ----
    float v[32];
#pragma unroll
    for (int i = 0; i < 32; ++i)
        v[i] = __bfloat162float(logT[(size_t)(g * 32 + i) * NTOK + base + s]);
    float mp = v[0];
#pragma unroll
    for (int i = 1; i < 32; ++i) mp = fmaxf(mp, v[i]);
    part[s][g] = mp;
    __syncthreads();
    float m = part[s][0];
#pragma unroll
    for (int i = 1; i < 8; ++i) m = fmaxf(m, part[s][i]);
    __syncthreads();
    float sum = 0.f;
#pragma unroll
    for (int i = 0; i < 32; ++i) { v[i] = __expf(v[i] - m); sum += v[i]; }
    part[s][g] = sum;
    __syncthreads();
    float tot = 0.f;
#pragma unroll
    for (int i = 0; i < 8; ++i) tot += part[s][i];
    const float inv = 1.f / tot;
#pragma unroll
    for (int i = 0; i < 32; ++i)
        ldsDist[g * 32 + i][s] = __float2bfloat16(v[i] * inv);

    // ---- fine half (independent; overlaps B2 chunk 0) ----
#pragma unroll
    for (int i = 0; i < 8; ++i) {
        const int sl = g * 8 + i;
        const float4 f = *reinterpret_cast<const float4*>(
            fine_w + (size_t)sid_l[sl] * HALF + s * 4);
        *reinterpret_cast<float4*>(out + (size_t)stok_l[sl] * 512 + s * 4) = f;
    }

    // ---- B2: mixture. wave g owns slots g*8..g*8+7; lane s -> cols s*4..s*4+3 ----
    float acc[8][4];
#pragma unroll
    for (int t = 0; t < 8; ++t)
#pragma unroll
        for (int c = 0; c < 4; ++c) acc[t][c] = 0.f;

    for (int ch = 0; ch < 16; ++ch) {
        __syncthreads();   // cw free (and ldsDist ready at ch==0)
        reinterpret_cast<float4*>(&cw[0][0])[tid]       = pre0;
        reinterpret_cast<float4*>(&cw[0][0])[tid + 512] = pre1;
        if (ch < 15) {
            const float4* nsrc = reinterpret_cast<const float4*>(
                coarse_w + (size_t)(ch + 1) * 16 * HALF);
            pre0 = nsrc[tid];
            pre1 = nsrc[tid + 512];
        }
        __syncthreads();   // cw ready
#pragma unroll
        for (int j = 0; j < 16; ++j) {
            const int k = ch * 16 + j;
            const uint4 dp = *reinterpret_cast<const uint4*>(&ldsDist[k][g * 8]); // broadcast
            const float4 wv = *reinterpret_cast<const float4*>(&cw[j][s * 4]);    // contiguous
            float d[8];
            d[0] = __uint_as_float(dp.x << 16);
            d[1] = __uint_as_float(dp.x & 0xffff0000u);
            d[2] = __uint_as_float(dp.y << 16);
            d[3] = __uint_as_float(dp.y & 0xffff0000u);
            d[4] = __uint_as_float(dp.z << 16);
            d[5] = __uint_as_float(dp.z & 0xffff0000u);
            d[6] = __uint_as_float(dp.w << 16);
            d[7] = __uint_as_float(dp.w & 0xffff0000u);
#pragma unroll
            for (int t = 0; t < 8; ++t) {
                acc[t][0] = fmaf(d[t], wv.x, acc[t][0]);
                acc[t][1] = fmaf(d[t], wv.y, acc[t][1]);
                acc[t][2] = fmaf(d[t], wv.z, acc[t][2]);
                acc[t][3] = fmaf(d[t], wv.w, acc[t][3]);
            }
        }
    }

    // epilogue: coarse half, coalesced 1KB per slot row
#pragma unroll
    for (int t = 0; t < 8; ++t) {
        float* o = out + (size_t)stok_l[g * 8 + t] * 512 + 256 + s * 4;
        *reinterpret_cast<float4*>(o) = make_float4(acc[t][0], acc[t][1], acc[t][2], acc[t][3]);
    }
}

// ---------------- Tier-2 fallback (round-4 kernel, needs only 155 KB ws) ----------------
#define TPB2 32
#define CK2  32
__global__ __launch_bounds__(512, 4)
void hle_t2(const int* __restrict__ ids, const float* __restrict__ fine_w,
            const float* __restrict__ coarse_w, const float* __restrict__ cluster_w,
            const float* __restrict__ cluster_b, const int* __restrict__ sorted,
            float* __restrict__ out)
{
    __shared__ float distT[NC][TPB2];
    __shared__ float cw_tile[CK2][HALF];
    __shared__ int   sid_tok[TPB2];
    __shared__ int   sid_id[TPB2];
    const int tid  = threadIdx.x;
    const int wave = tid >> 6;
    const int lane = tid & 63;
    const int base = blockIdx.x * TPB2;
    if (tid < TPB2) {
        const int tok = sorted[base + tid];
        sid_tok[tid] = tok;
        sid_id[tid]  = ids[tok];
    }
    __syncthreads();
    {
        const int tl = lane & 31;
        const int hi = lane >> 5;
        const int id = sid_id[tl];
        const int c0 = 2 * wave + hi;
        float lg[16];
#pragma unroll
        for (int k = 0; k < 16; ++k)
            lg[k] = cluster_w[(size_t)(c0 + 16 * k) * VOCAB + id];
#pragma unroll
        for (int k = 0; k < 16; ++k) {
            const int c = c0 + 16 * k;
            distT[c][tl ^ (c & 28)] = lg[k] + cluster_b[c];
        }
    }
    __syncthreads();
    {
        const int t0 = wave * 4;
#pragma unroll
        for (int i = 0; i < 4; ++i) {
            const int t = t0 + i;
            float v[4];
#pragma unroll
            for (int k = 0; k < 4; ++k) {
                const int c = lane + 64 * k;
                v[k] = distT[c][t ^ (c & 28)];
            }
            float m = fmaxf(fmaxf(v[0], v[1]), fmaxf(v[2], v[3]));
#pragma unroll
            for (int off = 32; off >= 1; off >>= 1) m = fmaxf(m, __shfl_xor(m, off));
            float e[4], sm = 0.f;
#pragma unroll
            for (int k = 0; k < 4; ++k) { e[k] = __expf(v[k] - m); sm += e[k]; }
#pragma unroll
            for (int off = 32; off >= 1; off >>= 1) sm += __shfl_xor(sm, off);
            const float inv = 1.f / sm;
#pragma unroll
            for (int k = 0; k < 4; ++k) {
                const int c = lane + 64 * k;
                distT[c][t ^ (c & 28)] = e[k] * inv;
            }
            const int tok = sid_tok[t];
            const float4 f = *reinterpret_cast<const float4*>(
                fine_w + (size_t)sid_id[t] * HALF + lane * 4);
            *reinterpret_cast<float4*>(out + (size_t)tok * 512 + lane * 4) = f;
        }
    }
    float acc[4][4] = {{0.f}};
    const int tg4 = wave * 4;
    const int colbase = lane * 4;
    for (int ch = 0; ch < NC / CK2; ++ch) {
        __syncthreads();
        {
            const float4* src = reinterpret_cast<const float4*>(coarse_w + (size_t)ch * CK2 * HALF);
            float4* dst = reinterpret_cast<float4*>(&cw_tile[0][0]);
#pragma unroll
            for (int p = 0; p < 4; ++p) dst[tid + p * 512] = src[tid + p * 512];
        }
        __syncthreads();
#pragma unroll 8
        for (int j = 0; j < CK2; ++j) {
            const int cc = ch * CK2 + j;
            const float4 d = *reinterpret_cast<const float4*>(&distT[cc][tg4 ^ (cc & 28)]);
            const float4 v = *reinterpret_cast<const float4*>(&cw_tile[j][colbase]);
            acc[0][0] = fmaf(d.x, v.x, acc[0][0]); acc[0][1] = fmaf(d.x, v.y, acc[0][1]);
            acc[0][2] = fmaf(d.x, v.z, acc[0][2]); acc[0][3] = fmaf(d.x, v.w, acc[0][3]);
            acc[1][0] = fmaf(d.y, v.x, acc[1][0]); acc[1][1] = fmaf(d.y, v.y, acc[1][1]);
            acc[1][2] = fmaf(d.y, v.z, acc[1][2]); acc[1][3] = fmaf(d.y, v.w, acc[1][3]);
            acc[2][0] = fmaf(d.z, v.x, acc[2][0]); acc[2][1] = fmaf(d.z, v.y, acc[2][1]);
            acc[2][2] = fmaf(d.z, v.z, acc[2][2]); acc[2][3] = fmaf(d.z, v.w, acc[2][3]);
            acc[3][0] = fmaf(d.w, v.x, acc[3][0]); acc[3][1] = fmaf(d.w, v.y, acc[3][1]);
            acc[3][2] = fmaf(d.w, v.z, acc[3][2]); acc[3][3] = fmaf(d.w, v.w, acc[3][3]);
        }
    }
#pragma unroll
    for (int jj = 0; jj < 4; ++jj) {
        const int tok = sid_tok[tg4 + jj];
        float* o = out + (size_t)tok * 512 + 256 + colbase;
        *reinterpret_cast<float4*>(o) = make_float4(acc[jj][0], acc[jj][1], acc[jj][2], acc[jj][3]);
    }
}

extern "C" void kernel_launch(void* const* d_in, const int* in_sizes, int n_in,
                              void* d_out, int out_size, void* d_ws, size_t ws_size,
                              hipStream_t stream) {
    const int*   ids       = (const int*)  d_in[0];
    const float* fine_w    = (const float*)d_in[1];
    const float* coarse_w  = (const float*)d_in[2];
    const float* cluster_w = (const float*)d_in[3];
    const float* cluster_b = (const float*)d_in[4];
    float*       out       = (float*)d_out;

    int* offs  = (int*)d_ws;            // [NBUCK]
    int* hist  = offs + NBUCK;          // [NBUCK]
    int* bexcl = hist + NBUCK;          // [NBUCK]
    int* stok  = bexcl + NBUCK;         // [NTOK]
    int* sidv  = stok + NTOK;           // [NTOK]
    __hip_bfloat16* logT = (__hip_bfloat16*)(sidv + NTOK);  // [NC*NTOK]

    const size_t needT2 = (size_t)(3 * NBUCK + 2 * NTOK) * sizeof(int);
    const size_t needT1 = needT2 + (size_t)NC * NTOK * sizeof(__hip_bfloat16);

    if (ws_size >= needT2) {
        hipMemsetAsync(hist, 0, NBUCK * sizeof(int), stream);
        hipLaunchKernelGGL(hist_kernel,    dim3(NTOK / 1024), dim3(1024), 0, stream, ids, hist);
        hipLaunchKernelGGL(scan_kernel,    dim3(1),           dim3(1024), 0, stream, hist, offs, bexcl);
        hipLaunchKernelGGL(scatter_kernel, dim3(NTOK / 1024), dim3(1024), 0, stream, ids, offs, stok, sidv);
    }

    if (ws_size >= needT1) {
        hipLaunchKernelGGL(gather_rows, dim3(NC * NSEG), dim3(256), 0, stream,
                           cluster_w, cluster_b, sidv, bexcl, logT);
        hipLaunchKernelGGL(mix_fine, dim3(NTOK / 64), dim3(512), 0, stream,
                           logT, fine_w, coarse_w, stok, sidv, out);
    } else if (ws_size >= needT2) {
        hipLaunchKernelGGL(hle_t2, dim3(NTOK / TPB2), dim3(512), 0, stream,
                           ids, fine_w, coarse_w, cluster_w, cluster_b, stok, out);
    }
    // (ws_size below tier-2 threshold is not expected for this harness)
}

// Round 7
// 58.970 us; speedup vs baseline: 1.3553x; 1.3188x over previous
//
#include <hip/hip_runtime.h>
#include <hip/hip_bf16.h>

#define VOCAB 100000
#define HALF  256      // HIDDEN/2
#define NC    256      // NUM_CLUSTERS
#define NTOK  16384    // B*S
#define NBUCK 2048     // id>>6 -> 0..1562, padded
#define SEGSZ 3200     // ids per segment (= 50 buckets of 64)
#define NSEG  32
#define BPS   50

using frag  = __attribute__((ext_vector_type(8))) short;   // 8 bf16 (A/B operand)
using f32x4 = __attribute__((ext_vector_type(4))) float;   // C/D

static __device__ inline unsigned bfpk(float lo, float hi) {
    union { __hip_bfloat162 h2; unsigned u; } cv;
    cv.h2.x = __float2bfloat16(lo);   // low 16 bits = first (even-k) element
    cv.h2.y = __float2bfloat16(hi);
    return cv.u;
}

// ---------------- prework ----------------
__global__ __launch_bounds__(1024)
void zero_hist(int* __restrict__ hist) {
    hist[blockIdx.x * 1024 + threadIdx.x] = 0;
}

__global__ __launch_bounds__(1024)
void hist_kernel(const int* __restrict__ ids, int* __restrict__ hist) {
    const int t = blockIdx.x * 1024 + threadIdx.x;
    atomicAdd(&hist[ids[t] >> 6], 1);
}

__global__ __launch_bounds__(1024)
void scan_kernel(const int* __restrict__ hist, int* __restrict__ offs,
                 int* __restrict__ bexcl) {
    __shared__ int part[1024];
    const int tid = threadIdx.x;
    const int h0 = hist[2 * tid], h1 = hist[2 * tid + 1];
    part[tid] = h0 + h1;
    __syncthreads();
    for (int off = 1; off < 1024; off <<= 1) {
        const int v   = part[tid];
        const int add = (tid >= off) ? part[tid - off] : 0;
        __syncthreads();
        part[tid] = v + add;
        __syncthreads();
    }
    const int excl = (tid == 0) ? 0 : part[tid - 1];
    offs[2 * tid]      = excl;
    offs[2 * tid + 1]  = excl + h0;
    bexcl[2 * tid]     = excl;
    bexcl[2 * tid + 1] = excl + h0;
}

__global__ __launch_bounds__(1024)
void scatter_kernel(const int* __restrict__ ids, int* __restrict__ offs,
                    int* __restrict__ stok, int* __restrict__ sidv) {
    const int t = blockIdx.x * 1024 + threadIdx.x;
    const int id = ids[t];
    const int pos = atomicAdd(&offs[id >> 6], 1);
    stok[pos] = t;
    sidv[pos] = id;
}

// coarse_w [c][h] f32 -> cT [h][c] bf16 (128 KB, L2-resident for kernel B)
__global__ __launch_bounds__(256)
void coarse_T(const float* __restrict__ cw, ushort* __restrict__ cT) {
    const int h = blockIdx.x;    // 0..255
    const int c = threadIdx.x;   // 0..255
    __hip_bfloat16 b = __float2bfloat16(cw[c * HALF + h]);
    cT[h * NC + c] = *reinterpret_cast<ushort*>(&b);
}

// ---------------- Kernel A: streaming logit gather ----------------
__global__ __launch_bounds__(256)
void gather_rows(const float* __restrict__ cluster_w,
                 const float* __restrict__ cluster_b,
                 const int*   __restrict__ sidv,
                 const int*   __restrict__ bexcl,
                 __hip_bfloat16* __restrict__ logT)      // [NC][NTOK]
{
    __shared__ float seg[SEGSZ];
    const int bid = blockIdx.x;
    const int r   = bid >> 5;          // 0..255
    const int s   = bid & 31;          // 0..31
    const int tid = threadIdx.x;
    const int sbase = s * SEGSZ;
    const int slen  = min(SEGSZ, VOCAB - sbase);

    const float4* src = reinterpret_cast<const float4*>(cluster_w + (size_t)r * VOCAB + sbase);
    float4* dst = reinterpret_cast<float4*>(seg);
    const int nf4 = slen >> 2;
    for (int i = tid; i < nf4; i += 256) dst[i] = src[i];

    const float bias = cluster_b[r];
    const int lo = bexcl[s * BPS];
    const int hi = bexcl[(s + 1) * BPS];
    __syncthreads();

    for (int i = lo + tid; i < hi; i += 256) {
        const int id = sidv[i];
        logT[(size_t)r * NTOK + i] = __float2bfloat16(seg[id - sbase] + bias);
    }
}

// ---------------- Kernel B: softmax + fine + MFMA mixture ----------------
// 512 blocks x 512 threads, 32 slots/block. LDS ~39 KB -> 2+ blocks/CU.
__global__ __launch_bounds__(512)
void mix_mfma(const ushort* __restrict__ logT,     // [NC][NTOK] bf16 bits
              const float*  __restrict__ fine_w,
              const ushort* __restrict__ cT,       // [HALF][NC] bf16 bits
              const int*    __restrict__ stok,
              const int*    __restrict__ sidv,
              float*        __restrict__ out)
{
    __shared__ uint4 ldsA[32][33];    // dist A-frags: [slot][kb], stride 528 B (2-way banks)
    __shared__ uint4 ldsB[256][5];    // cT chunk:     [n][kb2],  stride  80 B (2-way banks)
    __shared__ float redu[32][17];
    __shared__ int stok_l[32], sid_l[32];

    const int tid  = threadIdx.x;
    const int base = blockIdx.x * 32;

    if (tid < 32) { stok_l[tid] = stok[base + tid]; sid_l[tid] = sidv[base + tid]; }

    // ---- B1: softmax for slot s; thread (s, g) owns clusters g*16..g*16+15 ----
    const int s = tid & 31;
    const int g = tid >> 5;           // 0..15
    float v[16];
#pragma unroll
    for (int i = 0; i < 16; ++i) {
        const unsigned u = logT[(size_t)(g * 16 + i) * NTOK + base + s];
        v[i] = __uint_as_float(u << 16);           // bf16 -> f32 exact
    }
    float m = v[0];
#pragma unroll
    for (int i = 1; i < 16; ++i) m = fmaxf(m, v[i]);
    redu[s][g] = m;
    __syncthreads();
    float M = redu[s][0];
#pragma unroll
    for (int i = 1; i < 16; ++i) M = fmaxf(M, redu[s][i]);
    __syncthreads();                                // readers done before reuse
    float sum = 0.f;
#pragma unroll
    for (int i = 0; i < 16; ++i) { v[i] = __expf(v[i] - M); sum += v[i]; }
    redu[s][g] = sum;
    __syncthreads();
    float tot = 0.f;
#pragma unroll
    for (int i = 0; i < 16; ++i) tot += redu[s][i];
    const float inv = 1.f / tot;

    // pack 16 dist values -> 2 A-frag uint4 (k ascending within short8)
    {
        uint4 u0, u1;
        u0.x = bfpk(v[0] * inv,  v[1] * inv);
        u0.y = bfpk(v[2] * inv,  v[3] * inv);
        u0.z = bfpk(v[4] * inv,  v[5] * inv);
        u0.w = bfpk(v[6] * inv,  v[7] * inv);
        u1.x = bfpk(v[8] * inv,  v[9] * inv);
        u1.y = bfpk(v[10] * inv, v[11] * inv);
        u1.z = bfpk(v[12] * inv, v[13] * inv);
        u1.w = bfpk(v[14] * inv, v[15] * inv);
        ldsA[s][2 * g]     = u0;
        ldsA[s][2 * g + 1] = u1;
    }

    // ---- fine half of output (independent; overlaps LDS settling) ----
    {
        const int sl = tid >> 4, l16 = tid & 15;
        const float4* fs = reinterpret_cast<const float4*>(fine_w + (size_t)sid_l[sl] * HALF);
        float4* fd = reinterpret_cast<float4*>(out + (size_t)stok_l[sl] * 512);
#pragma unroll
        for (int p = 0; p < 4; ++p) fd[l16 + 16 * p] = fs[l16 + 16 * p];
    }

    // ---- B2: MFMA mixture. wave w: m-tile = w&1, n-tiles = (w>>1)*4 + q ----
    const int w    = tid >> 6;
    const int lane = tid & 63;
    const int arow = (w & 1) * 16 + (lane & 15);
    const int ngrp = (w >> 1) * 4;
    f32x4 acc[4];
#pragma unroll
    for (int q = 0; q < 4; ++q) acc[q] = (f32x4){0.f, 0.f, 0.f, 0.f};

    for (int ch = 0; ch < 8; ++ch) {
        __syncthreads();   // ldsB consumed (and at ch=0: ldsA fully written)
#pragma unroll
        for (int p = 0; p < 2; ++p) {
            const int idx = tid + p * 512;
            const int n = idx >> 2, kb2 = idx & 3;
            ldsB[n][kb2] = *reinterpret_cast<const uint4*>(cT + (size_t)n * NC + ch * 32 + kb2 * 8);
        }
        __syncthreads();

        const frag a = *reinterpret_cast<const frag*>(&ldsA[arow][ch * 4 + (lane >> 4)]);
#pragma unroll
        for (int q = 0; q < 4; ++q) {
            const int nt = ngrp + q;
            const frag b = *reinterpret_cast<const frag*>(&ldsB[nt * 16 + (lane & 15)][lane >> 4]);
            acc[q] = __builtin_amdgcn_mfma_f32_16x16x32_bf16(a, b, acc[q], 0, 0, 0);
        }
    }

    // ---- epilogue: C/D map col=lane&15, row=(lane>>4)*4+reg (HW-verified) ----
#pragma unroll
    for (int q = 0; q < 4; ++q) {
        const int col = (ngrp + q) * 16 + (lane & 15);
#pragma unroll
        for (int r = 0; r < 4; ++r) {
            const int srow = (w & 1) * 16 + (lane >> 4) * 4 + r;
            out[(size_t)stok_l[srow] * 512 + 256 + col] = acc[q][r];
        }
    }
}

extern "C" void kernel_launch(void* const* d_in, const int* in_sizes, int n_in,
                              void* d_out, int out_size, void* d_ws, size_t ws_size,
                              hipStream_t stream) {
    const int*   ids       = (const int*)  d_in[0];
    const float* fine_w    = (const float*)d_in[1];
    const float* coarse_w  = (const float*)d_in[2];
    const float* cluster_w = (const float*)d_in[3];
    const float* cluster_b = (const float*)d_in[4];
    float*       out       = (float*)d_out;

    int* offs  = (int*)d_ws;            // [NBUCK]
    int* hist  = offs + NBUCK;          // [NBUCK]
    int* bexcl = hist + NBUCK;          // [NBUCK]
    int* stok  = bexcl + NBUCK;         // [NTOK]
    int* sidv  = stok + NTOK;           // [NTOK]
    __hip_bfloat16* logT = (__hip_bfloat16*)(sidv + NTOK);        // [NC*NTOK] bf16
    ushort* cT = (ushort*)(logT + (size_t)NC * NTOK);             // [HALF*NC] bf16

    const size_t need = (size_t)(3 * NBUCK + 2 * NTOK) * sizeof(int)
                      + (size_t)NC * NTOK * 2 + (size_t)HALF * NC * 2;
    if (ws_size < need) return;   // not expected

    hipLaunchKernelGGL(zero_hist,      dim3(NBUCK / 1024), dim3(1024), 0, stream, hist);
    hipLaunchKernelGGL(coarse_T,       dim3(HALF),         dim3(256),  0, stream, coarse_w, cT);
    hipLaunchKernelGGL(hist_kernel,    dim3(NTOK / 1024),  dim3(1024), 0, stream, ids, hist);
    hipLaunchKernelGGL(scan_kernel,    dim3(1),            dim3(1024), 0, stream, hist, offs, bexcl);
    hipLaunchKernelGGL(scatter_kernel, dim3(NTOK / 1024),  dim3(1024), 0, stream, ids, offs, stok, sidv);
    hipLaunchKernelGGL(gather_rows,    dim3(NC * NSEG),    dim3(256),  0, stream,
                       cluster_w, cluster_b, sidv, bexcl, logT);
    hipLaunchKernelGGL(mix_mfma,       dim3(NTOK / 32),    dim3(512),  0, stream,
                       (const ushort*)logT, fine_w, cT, stok, sidv, out);
}

// Round 8
// 58.359 us; speedup vs baseline: 1.3695x; 1.0105x over previous
//
#include <hip/hip_runtime.h>
#include <hip/hip_bf16.h>

#define VOCAB 100000
#define HALF  256      // HIDDEN/2
#define NC    256      // NUM_CLUSTERS
#define NTOK  16384    // B*S
#define NBUCK 2048     // id>>6 -> 0..1562, padded
#define SEGSZ 3200     // ids per segment (= 50 buckets of 64)
#define NSEG  32
#define BPS   50
#define NHB   16       // histogram blocks

using frag  = __attribute__((ext_vector_type(8))) short;   // 8 bf16 (A/B operand)
using f32x4 = __attribute__((ext_vector_type(4))) float;   // C/D

static __device__ inline unsigned bfpk(float lo, float hi) {
    union { __hip_bfloat162 h2; unsigned u; } cv;
    cv.h2.x = __float2bfloat16(lo);
    cv.h2.y = __float2bfloat16(hi);
    return cv.u;
}

// ---------------- prep1: per-block histograms + coarse transpose ----------------
// blocks 0..15: LDS histogram of 1024 ids -> partial[b][NBUCK]
// blocks 16..31: 64x64 LDS transpose tile of coarse_w -> cT bf16
__global__ __launch_bounds__(1024)
void prep1(const int* __restrict__ ids, const float* __restrict__ coarse_w,
           int* __restrict__ partial, ushort* __restrict__ cT)
{
    __shared__ float tile[64][65];                  // 16.6 KB (coarse blocks)
    __shared__ int lh[NBUCK];                       // 8 KB   (hist blocks)
    const int tid = threadIdx.x;
    const int b   = blockIdx.x;

    if (b < NHB) {
        lh[tid] = 0; lh[tid + 1024] = 0;
        __syncthreads();
        atomicAdd(&lh[ids[b * 1024 + tid] >> 6], 1);
        __syncthreads();
        partial[b * NBUCK + tid]        = lh[tid];
        partial[b * NBUCK + tid + 1024] = lh[tid + 1024];
    } else {
        const int bt = b - NHB;
        const int ci = (bt >> 2) * 64, hi = (bt & 3) * 64;
#pragma unroll
        for (int p = 0; p < 4; ++p) {
            const int idx = tid + p * 1024;
            const int cl = idx >> 6, hl = idx & 63;
            tile[cl][hl] = coarse_w[(size_t)(ci + cl) * HALF + hi + hl];
        }
        __syncthreads();
#pragma unroll
        for (int p = 0; p < 4; ++p) {
            const int idx = tid + p * 1024;
            const int hl = idx >> 6, cl = idx & 63;
            __hip_bfloat16 v = __float2bfloat16(tile[cl][hl]);
            cT[(size_t)(hi + hl) * NC + ci + cl] = *reinterpret_cast<ushort*>(&v);
        }
    }
}

// ---------------- prep2: redundant scan + rank scatter (no global atomics) ----------------
__global__ __launch_bounds__(1024)
void prep2(const int* __restrict__ ids, const int* __restrict__ partial,
           int* __restrict__ bexcl, int* __restrict__ stok, int* __restrict__ sidv)
{
    __shared__ int A_[NBUCK], B_[NBUCK], base_[NBUCK], lcnt_[NBUCK];   // 32 KB
    const int tid = threadIdx.x;
    const int b   = blockIdx.x;

#pragma unroll
    for (int p = 0; p < 2; ++p) {
        const int e = tid + p * 1024;
        int tot = 0, bas = 0;
#pragma unroll
        for (int bb = 0; bb < NHB; ++bb) {
            const int v = partial[bb * NBUCK + e];
            tot += v;
            if (bb < b) bas += v;
        }
        A_[e] = tot; base_[e] = bas; lcnt_[e] = 0;
    }
    __syncthreads();

    int* src = A_; int* dst = B_;
    for (int off = 1; off < NBUCK; off <<= 1) {
#pragma unroll
        for (int p = 0; p < 2; ++p) {
            const int e = tid + p * 1024;
            dst[e] = src[e] + (e >= off ? src[e - off] : 0);
        }
        __syncthreads();
        int* tmp = src; src = dst; dst = tmp;
    }
    // src = inclusive scan; build exclusive in dst
#pragma unroll
    for (int p = 0; p < 2; ++p) {
        const int e = tid + p * 1024;
        dst[e] = e ? src[e - 1] : 0;
    }
    __syncthreads();

    if (b == 0) {
#pragma unroll
        for (int p = 0; p < 2; ++p) {
            const int e = tid + p * 1024;
            bexcl[e] = dst[e];
        }
    }

    const int t  = b * 1024 + tid;
    const int id = ids[t];
    const int k  = id >> 6;
    const int r  = atomicAdd(&lcnt_[k], 1);            // LDS atomic
    const int pos = dst[k] + base_[k] + r;
    stok[pos] = t;
    sidv[pos] = id;
}

// ---------------- Kernel A: streaming logit gather ----------------
__global__ __launch_bounds__(256)
void gather_rows(const float* __restrict__ cluster_w,
                 const float* __restrict__ cluster_b,
                 const int*   __restrict__ sidv,
                 const int*   __restrict__ bexcl,
                 __hip_bfloat16* __restrict__ logT)      // [NC][NTOK]
{
    __shared__ float seg[SEGSZ];
    const int bid = blockIdx.x;
    const int r   = bid >> 5;
    const int s   = bid & 31;
    const int tid = threadIdx.x;
    const int sbase = s * SEGSZ;
    const int slen  = min(SEGSZ, VOCAB - sbase);

    const float4* src = reinterpret_cast<const float4*>(cluster_w + (size_t)r * VOCAB + sbase);
    float4* dst = reinterpret_cast<float4*>(seg);
    const int nf4 = slen >> 2;
    for (int i = tid; i < nf4; i += 256) dst[i] = src[i];

    const float bias = cluster_b[r];
    const int lo = bexcl[s * BPS];
    const int hi = bexcl[(s + 1) * BPS];
    __syncthreads();

    for (int i = lo + tid; i < hi; i += 256) {
        const int id = sidv[i];
        logT[(size_t)r * NTOK + i] = __float2bfloat16(seg[id - sbase] + bias);
    }
}

// ---------------- Kernel B: softmax + fine + MFMA mixture (B direct from L2) ----------------
__global__ __launch_bounds__(512)
void mix_mfma(const ushort* __restrict__ logT,     // [NC][NTOK] bf16 bits
              const float*  __restrict__ fine_w,
              const ushort* __restrict__ cT,       // [HALF][NC] bf16 bits, L2-hot
              const int*    __restrict__ stok,
              const int*    __restrict__ sidv,
              float*        __restrict__ out)
{
    __shared__ uint4 ldsA[32][33];    // dist A-frags, stride 528 B (2-way banks)
    __shared__ float redu[32][17];
    __shared__ int stok_l[32], sid_l[32];

    const int tid  = threadIdx.x;
    const int base = blockIdx.x * 32;

    if (tid < 32) { stok_l[tid] = stok[base + tid]; sid_l[tid] = sidv[base + tid]; }

    // ---- B1: softmax for slot s; thread (s, g) owns clusters g*16..g*16+15 ----
    const int s = tid & 31;
    const int g = tid >> 5;           // 0..15
    float v[16];
#pragma unroll
    for (int i = 0; i < 16; ++i) {
        const unsigned u = logT[(size_t)(g * 16 + i) * NTOK + base + s];
        v[i] = __uint_as_float(u << 16);
    }
    float m = v[0];
#pragma unroll
    for (int i = 1; i < 16; ++i) m = fmaxf(m, v[i]);
    redu[s][g] = m;
    __syncthreads();
    float M = redu[s][0];
#pragma unroll
    for (int i = 1; i < 16; ++i) M = fmaxf(M, redu[s][i]);
    __syncthreads();
    float sum = 0.f;
#pragma unroll
    for (int i = 0; i < 16; ++i) { v[i] = __expf(v[i] - M); sum += v[i]; }
    redu[s][g] = sum;
    __syncthreads();
    float tot = 0.f;
#pragma unroll
    for (int i = 0; i < 16; ++i) tot += redu[s][i];
    const float inv = 1.f / tot;

    {
        uint4 u0, u1;
        u0.x = bfpk(v[0] * inv,  v[1] * inv);
        u0.y = bfpk(v[2] * inv,  v[3] * inv);
        u0.z = bfpk(v[4] * inv,  v[5] * inv);
        u0.w = bfpk(v[6] * inv,  v[7] * inv);
        u1.x = bfpk(v[8] * inv,  v[9] * inv);
        u1.y = bfpk(v[10] * inv, v[11] * inv);
        u1.z = bfpk(v[12] * inv, v[13] * inv);
        u1.w = bfpk(v[14] * inv, v[15] * inv);
        ldsA[s][2 * g]     = u0;
        ldsA[s][2 * g + 1] = u1;
    }

    // ---- fine half of output ----
    {
        const int sl = tid >> 4, l16 = tid & 15;
        const float4* fs = reinterpret_cast<const float4*>(fine_w + (size_t)sid_l[sl] * HALF);
        float4* fd = reinterpret_cast<float4*>(out + (size_t)stok_l[sl] * 512);
#pragma unroll
        for (int p = 0; p < 4; ++p) fd[l16 + 16 * p] = fs[l16 + 16 * p];
    }
    __syncthreads();   // ldsA ready for cross-thread reads

    // ---- B2: MFMA; A from LDS, B direct from cT (L2). No barriers. ----
    const int w    = tid >> 6;
    const int lane = tid & 63;
    const int arow = (w & 1) * 16 + (lane & 15);
    const int ngrp = (w >> 1) * 4;
    f32x4 acc[4];
#pragma unroll
    for (int q = 0; q < 4; ++q) acc[q] = (f32x4){0.f, 0.f, 0.f, 0.f};

    for (int ch = 0; ch < 8; ++ch) {
        const frag a = *reinterpret_cast<const frag*>(&ldsA[arow][ch * 4 + (lane >> 4)]);
#pragma unroll
        for (int q = 0; q < 4; ++q) {
            const int n = (ngrp + q) * 16 + (lane & 15);
            const frag b = *reinterpret_cast<const frag*>(
                cT + (size_t)n * NC + ch * 32 + (lane >> 4) * 8);
            acc[q] = __builtin_amdgcn_mfma_f32_16x16x32_bf16(a, b, acc[q], 0, 0, 0);
        }
    }

    // ---- epilogue: C/D map col=lane&15, row=(lane>>4)*4+reg ----
#pragma unroll
    for (int q = 0; q < 4; ++q) {
        const int col = (ngrp + q) * 16 + (lane & 15);
#pragma unroll
        for (int r = 0; r < 4; ++r) {
            const int srow = (w & 1) * 16 + (lane >> 4) * 4 + r;
            out[(size_t)stok_l[srow] * 512 + 256 + col] = acc[q][r];
        }
    }
}

extern "C" void kernel_launch(void* const* d_in, const int* in_sizes, int n_in,
                              void* d_out, int out_size, void* d_ws, size_t ws_size,
                              hipStream_t stream) {
    const int*   ids       = (const int*)  d_in[0];
    const float* fine_w    = (const float*)d_in[1];
    const float* coarse_w  = (const float*)d_in[2];
    const float* cluster_w = (const float*)d_in[3];
    const float* cluster_b = (const float*)d_in[4];
    float*       out       = (float*)d_out;

    int* partial = (int*)d_ws;                    // [NHB][NBUCK]
    int* bexcl   = partial + NHB * NBUCK;         // [NBUCK]
    int* stok    = bexcl + NBUCK;                 // [NTOK]
    int* sidv    = stok + NTOK;                   // [NTOK]
    __hip_bfloat16* logT = (__hip_bfloat16*)(sidv + NTOK);   // [NC*NTOK]
    ushort* cT = (ushort*)(logT + (size_t)NC * NTOK);        // [HALF*NC]

    const size_t need = (size_t)(NHB * NBUCK + NBUCK + 2 * NTOK) * sizeof(int)
                      + (size_t)NC * NTOK * 2 + (size_t)HALF * NC * 2;
    if (ws_size < need) return;   // not expected

    hipLaunchKernelGGL(prep1, dim3(2 * NHB), dim3(1024), 0, stream,
                       ids, coarse_w, partial, cT);
    hipLaunchKernelGGL(prep2, dim3(NHB), dim3(1024), 0, stream,
                       ids, partial, bexcl, stok, sidv);
    hipLaunchKernelGGL(gather_rows, dim3(NC * NSEG), dim3(256), 0, stream,
                       cluster_w, cluster_b, sidv, bexcl, logT);
    hipLaunchKernelGGL(mix_mfma, dim3(NTOK / 32), dim3(512), 0, stream,
                       (const ushort*)logT, fine_w, cT, stok, sidv, out);
}

// Round 9
// 58.163 us; speedup vs baseline: 1.3741x; 1.0034x over previous
//
#include <hip/hip_runtime.h>
#include <hip/hip_bf16.h>

#define VOCAB 100000
#define HALF  256      // HIDDEN/2
#define NC    256      // NUM_CLUSTERS
#define NTOK  16384    // B*S
#define SEGSZ 3200     // ids per segment
#define NSEG  32
#define NHB   16       // histogram/scatter blocks

using frag  = __attribute__((ext_vector_type(8))) short;   // 8 bf16 (A/B operand)
using f32x4 = __attribute__((ext_vector_type(4))) float;   // C/D

static __device__ inline unsigned bfpk(float lo, float hi) {
    union { __hip_bfloat162 h2; unsigned u; } cv;
    cv.h2.x = __float2bfloat16(lo);
    cv.h2.y = __float2bfloat16(hi);
    return cv.u;
}

// ---------------- prep1: 32-seg histograms + coarse transpose ----------------
// blocks 0..15: 32-counter LDS histogram of 1024 ids -> partial[b][NSEG]
// blocks 16..31: 64x64 LDS-transpose tile of coarse_w -> cT bf16
__global__ __launch_bounds__(1024)
void prep1(const int* __restrict__ ids, const float* __restrict__ coarse_w,
           int* __restrict__ partial, ushort* __restrict__ cT)
{
    __shared__ float tile[64][65];
    __shared__ int lh[NSEG];
    const int tid = threadIdx.x;
    const int b   = blockIdx.x;

    if (b < NHB) {
        if (tid < NSEG) lh[tid] = 0;
        __syncthreads();
        atomicAdd(&lh[ids[b * 1024 + tid] / SEGSZ], 1);
        __syncthreads();
        if (tid < NSEG) partial[b * NSEG + tid] = lh[tid];
    } else {
        const int bt = b - NHB;
        const int ci = (bt >> 2) * 64, hi = (bt & 3) * 64;
#pragma unroll
        for (int p = 0; p < 4; ++p) {
            const int idx = tid + p * 1024;
            const int cl = idx >> 6, hl = idx & 63;
            tile[cl][hl] = coarse_w[(size_t)(ci + cl) * HALF + hi + hl];
        }
        __syncthreads();
#pragma unroll
        for (int p = 0; p < 4; ++p) {
            const int idx = tid + p * 1024;
            const int hl = idx >> 6, cl = idx & 63;
            __hip_bfloat16 v = __float2bfloat16(tile[cl][hl]);
            cT[(size_t)(hi + hl) * NC + ci + cl] = *reinterpret_cast<ushort*>(&v);
        }
    }
}

// ---------------- prep2: 32-wide offsets + rank scatter ----------------
__global__ __launch_bounds__(1024)
void prep2(const int* __restrict__ ids, const int* __restrict__ partial,
           int* __restrict__ seg_off, int* __restrict__ stok, int* __restrict__ sidv)
{
    __shared__ int part_l[NHB][NSEG];   // 2 KB
    __shared__ int segoff[NSEG + 1];
    __shared__ int basebs[NSEG];
    __shared__ int cnt[NSEG];
    const int tid = threadIdx.x;
    const int b   = blockIdx.x;

    if (tid < NHB * NSEG) part_l[tid >> 5][tid & 31] = partial[tid];
    __syncthreads();

    if (tid < NSEG) {
        int tot_before = 0;   // sum over all blocks, segments < tid
        int tot_s = 0;        // segment tid total
        int base  = 0;        // segment tid, blocks < b
        for (int bb = 0; bb < NHB; ++bb) {
            const int v = part_l[bb][tid];
            tot_s += v;
            if (bb < b) base += v;
        }
        for (int s = 0; s < NSEG; ++s) {
            if (s < tid) {
                for (int bb = 0; bb < NHB; ++bb) tot_before += part_l[bb][s];
            }
        }
        segoff[tid] = tot_before;
        basebs[tid] = base;
        cnt[tid]    = 0;
        if (tid == NSEG - 1) segoff[NSEG] = tot_before + tot_s;
    }
    __syncthreads();

    const int t  = b * 1024 + tid;
    const int id = ids[t];
    const int sg = id / SEGSZ;
    const int r  = atomicAdd(&cnt[sg], 1);
    const int pos = segoff[sg] + basebs[sg] + r;
    stok[pos] = t;
    sidv[pos] = id;

    if (b == 0 && tid <= NSEG) seg_off[tid] = segoff[tid];
}

// ---------------- Kernel A: streaming logit gather ----------------
__global__ __launch_bounds__(256)
void gather_rows(const float* __restrict__ cluster_w,
                 const float* __restrict__ cluster_b,
                 const int*   __restrict__ sidv,
                 const int*   __restrict__ seg_off,
                 __hip_bfloat16* __restrict__ logT)      // [NC][NTOK]
{
    __shared__ float seg[SEGSZ];
    const int bid = blockIdx.x;
    const int r   = bid >> 5;
    const int s   = bid & 31;
    const int tid = threadIdx.x;
    const int sbase = s * SEGSZ;
    const int slen  = min(SEGSZ, VOCAB - sbase);

    const float4* src = reinterpret_cast<const float4*>(cluster_w + (size_t)r * VOCAB + sbase);
    float4* dst = reinterpret_cast<float4*>(seg);
    const int nf4 = slen >> 2;
    for (int i = tid; i < nf4; i += 256) dst[i] = src[i];

    const float bias = cluster_b[r];
    const int lo = seg_off[s];
    const int hi = seg_off[s + 1];
    __syncthreads();

    for (int i = lo + tid; i < hi; i += 256) {
        const int id = sidv[i];
        logT[(size_t)r * NTOK + i] = __float2bfloat16(seg[id - sbase] + bias);
    }
}

// ---------------- Kernel B: softmax + fine + MFMA mixture ----------------
__global__ __launch_bounds__(512)
void mix_mfma(const ushort* __restrict__ logT,     // [NC][NTOK] bf16 bits
              const float*  __restrict__ fine_w,
              const ushort* __restrict__ cT,       // [HALF][NC] bf16 bits, L2-hot
              const int*    __restrict__ stok,
              const int*    __restrict__ sidv,
              float*        __restrict__ out)
{
    __shared__ uint4 ldsA[32][33];    // dist A-frags, stride 528 B (2-way banks)
    __shared__ float redu[32][17];
    __shared__ int stok_l[32], sid_l[32];

    const int tid  = threadIdx.x;
    const int base = blockIdx.x * 32;

    if (tid < 32) { stok_l[tid] = stok[base + tid]; sid_l[tid] = sidv[base + tid]; }

    // ---- B1: softmax for slot s; thread (s, g) owns clusters g*16..g*16+15 ----
    const int s = tid & 31;
    const int g = tid >> 5;           // 0..15
    float v[16];
#pragma unroll
    for (int i = 0; i < 16; ++i) {
        const unsigned u = logT[(size_t)(g * 16 + i) * NTOK + base + s];
        v[i] = __uint_as_float(u << 16);
    }
    float m = v[0];
#pragma unroll
    for (int i = 1; i < 16; ++i) m = fmaxf(m, v[i]);
    redu[s][g] = m;
    __syncthreads();
    float M = redu[s][0];
#pragma unroll
    for (int i = 1; i < 16; ++i) M = fmaxf(M, redu[s][i]);
    __syncthreads();
    float sum = 0.f;
#pragma unroll
    for (int i = 0; i < 16; ++i) { v[i] = __expf(v[i] - M); sum += v[i]; }
    redu[s][g] = sum;
    __syncthreads();
    float tot = 0.f;
#pragma unroll
    for (int i = 0; i < 16; ++i) tot += redu[s][i];
    const float inv = 1.f / tot;

    {
        uint4 u0, u1;
        u0.x = bfpk(v[0] * inv,  v[1] * inv);
        u0.y = bfpk(v[2] * inv,  v[3] * inv);
        u0.z = bfpk(v[4] * inv,  v[5] * inv);
        u0.w = bfpk(v[6] * inv,  v[7] * inv);
        u1.x = bfpk(v[8] * inv,  v[9] * inv);
        u1.y = bfpk(v[10] * inv, v[11] * inv);
        u1.z = bfpk(v[12] * inv, v[13] * inv);
        u1.w = bfpk(v[14] * inv, v[15] * inv);
        ldsA[s][2 * g]     = u0;
        ldsA[s][2 * g + 1] = u1;
    }

    // ---- fine half of output ----
    {
        const int sl = tid >> 4, l16 = tid & 15;
        const float4* fs = reinterpret_cast<const float4*>(fine_w + (size_t)sid_l[sl] * HALF);
        float4* fd = reinterpret_cast<float4*>(out + (size_t)stok_l[sl] * 512);
#pragma unroll
        for (int p = 0; p < 4; ++p) fd[l16 + 16 * p] = fs[l16 + 16 * p];
    }
    __syncthreads();   // ldsA ready for cross-thread reads

    // ---- B2: MFMA; A from LDS, B direct from cT (L2). No barriers. ----
    const int w    = tid >> 6;
    const int lane = tid & 63;
    const int arow = (w & 1) * 16 + (lane & 15);
    const int ngrp = (w >> 1) * 4;
    f32x4 acc[4];
#pragma unroll
    for (int q = 0; q < 4; ++q) acc[q] = (f32x4){0.f, 0.f, 0.f, 0.f};

    for (int ch = 0; ch < 8; ++ch) {
        const frag a = *reinterpret_cast<const frag*>(&ldsA[arow][ch * 4 + (lane >> 4)]);
#pragma unroll
        for (int q = 0; q < 4; ++q) {
            const int n = (ngrp + q) * 16 + (lane & 15);
            const frag b = *reinterpret_cast<const frag*>(
                cT + (size_t)n * NC + ch * 32 + (lane >> 4) * 8);
            acc[q] = __builtin_amdgcn_mfma_f32_16x16x32_bf16(a, b, acc[q], 0, 0, 0);
        }
    }

    // ---- epilogue: C/D map col=lane&15, row=(lane>>4)*4+reg ----
#pragma unroll
    for (int q = 0; q < 4; ++q) {
        const int col = (ngrp + q) * 16 + (lane & 15);
#pragma unroll
        for (int r = 0; r < 4; ++r) {
            const int srow = (w & 1) * 16 + (lane >> 4) * 4 + r;
            out[(size_t)stok_l[srow] * 512 + 256 + col] = acc[q][r];
        }
    }
}

extern "C" void kernel_launch(void* const* d_in, const int* in_sizes, int n_in,
                              void* d_out, int out_size, void* d_ws, size_t ws_size,
                              hipStream_t stream) {
    const int*   ids       = (const int*)  d_in[0];
    const float* fine_w    = (const float*)d_in[1];
    const float* coarse_w  = (const float*)d_in[2];
    const float* cluster_w = (const float*)d_in[3];
    const float* cluster_b = (const float*)d_in[4];
    float*       out       = (float*)d_out;

    int* partial = (int*)d_ws;                    // [NHB*NSEG]
    int* seg_off = partial + NHB * NSEG;          // [NSEG+1] (pad 64)
    int* stok    = seg_off + 64;                  // [NTOK]
    int* sidv    = stok + NTOK;                   // [NTOK]
    __hip_bfloat16* logT = (__hip_bfloat16*)(sidv + NTOK);   // [NC*NTOK]
    ushort* cT = (ushort*)(logT + (size_t)NC * NTOK);        // [HALF*NC]

    const size_t need = (size_t)(NHB * NSEG + 64 + 2 * NTOK) * sizeof(int)
                      + (size_t)NC * NTOK * 2 + (size_t)HALF * NC * 2;
    if (ws_size < need) return;   // not expected

    hipLaunchKernelGGL(prep1, dim3(2 * NHB), dim3(1024), 0, stream,
                       ids, coarse_w, partial, cT);
    hipLaunchKernelGGL(prep2, dim3(NHB), dim3(1024), 0, stream,
                       ids, partial, seg_off, stok, sidv);
    hipLaunchKernelGGL(gather_rows, dim3(NC * NSEG), dim3(256), 0, stream,
                       cluster_w, cluster_b, sidv, seg_off, logT);
    hipLaunchKernelGGL(mix_mfma, dim3(NTOK / 32), dim3(512), 0, stream,
                       (const ushort*)logT, fine_w, cT, stok, sidv, out);
}